// Round 4
// baseline (1436.813 us; speedup 1.0000x reference)
//
#include <hip/hip_runtime.h>

#define NSITES 500000
#define KOFF   27
#define RPAIR  250000
#define KR     (KOFF * RPAIR)            // 6,750,000 pairs
#define CIN    16
#define COUT   16

#define NBUCK  1954                      // ceil(NSITES/256)
#define NSEG   (NBUCK * KOFF)            // 52,758 segments (bucket-major, k-minor)
#define ASTRIDE 17                       // LDS acc row stride (bank spread)

// ---------------- workspace layout (int32 slots) ----------------
// cur      [0,      NSEG)        segment cursor (histogram -> cursor)
// segstart [65536,  65536+NSEG+1)
// entries  [131072, 131072+KR)   packed (in | k<<19 | o_local<<24)

// ---------------------------------------------------------------------------
// Pass 1: per-segment histogram
// ---------------------------------------------------------------------------
__global__ __launch_bounds__(256) void subhist_kernel(
    const int* __restrict__ rules_out, int* __restrict__ cur)
{
    const int k = blockIdx.y;
    const int r = blockIdx.x * blockDim.x + threadIdx.x;
    if (r >= RPAIR) return;
    const int o = rules_out[k * RPAIR + r];
    atomicAdd(cur + ((o >> 8) * KOFF + k), 1);
}

// ---------------------------------------------------------------------------
// Pass 2: single-block exclusive scan of 52758 counts -> segstart, cur=start
// ---------------------------------------------------------------------------
__global__ __launch_bounds__(1024) void seg_scan_kernel(
    int* __restrict__ cur, int* __restrict__ segstart)
{
    __shared__ int s[1024];
    __shared__ int base_s;
    const int t = threadIdx.x;
    if (t == 0) base_s = 0;
    __syncthreads();
    for (int chunk = 0; chunk < (NSEG + 1023) / 1024; ++chunk) {
        const int i = chunk * 1024 + t;
        const int v = (i < NSEG) ? cur[i] : 0;
        s[t] = v;
        __syncthreads();
        for (int off = 1; off < 1024; off <<= 1) {   // inclusive Hillis-Steele
            int u = (t >= off) ? s[t - off] : 0;
            __syncthreads();
            s[t] += u;
            __syncthreads();
        }
        const int excl = base_s + s[t] - v;
        if (i < NSEG) { segstart[i] = excl; cur[i] = excl; }
        __syncthreads();
        if (t == 1023) base_s += s[1023];
        __syncthreads();
    }
    if (t == 0) segstart[NSEG] = KR;
}

// ---------------------------------------------------------------------------
// Pass 3: scatter pairs into segment-major entries (frontier writes -> no
// write amplification). entry = in | k<<19 | (o&255)<<24
// ---------------------------------------------------------------------------
__global__ __launch_bounds__(256) void scatter_kernel(
    const int* __restrict__ rules_in, const int* __restrict__ rules_out,
    int* __restrict__ cur, int* __restrict__ entries)
{
    const int k = blockIdx.y;
    const int r = blockIdx.x * blockDim.x + threadIdx.x;
    if (r >= RPAIR) return;
    const int p  = k * RPAIR + r;
    const int o  = rules_out[p];
    const int in = rules_in[p];
    const int pos = atomicAdd(cur + ((o >> 8) * KOFF + k), 1);
    entries[pos] = in | (k << 19) | ((o & 255) << 24);
}

// ---------------------------------------------------------------------------
// Pass 4: one block per bucket. LDS f32 accumulators (256 rows x 16, stride
// 17). Entries are k-sorted -> W loads are wave-uniform (L1 broadcast).
// Each output row written exactly once, coalesced, with bias.
// ---------------------------------------------------------------------------
__device__ inline void fma4(float4& a, float s, const float4 w) {
    a.x = fmaf(s, w.x, a.x);
    a.y = fmaf(s, w.y, a.y);
    a.z = fmaf(s, w.z, a.z);
    a.w = fmaf(s, w.w, a.w);
}

__global__ __launch_bounds__(256) void bucket_gemm_kernel(
    const float* __restrict__ features,
    const float* __restrict__ weight,
    const float* __restrict__ bias,
    const int*   __restrict__ segstart,
    const int*   __restrict__ entries,
    float*       __restrict__ out)
{
    __shared__ float acc[256 * ASTRIDE];
    const int b   = blockIdx.x;
    const int tid = threadIdx.x;

    for (int i = tid; i < 256 * ASTRIDE; i += 256) acc[i] = 0.f;
    __syncthreads();

    const int s = segstart[b * KOFF];
    const int e = segstart[b * KOFF + KOFF];

    for (int i = s + tid; i < e; i += 256) {
        const unsigned v = (unsigned)entries[i];
        const int in = v & 0x7FFFF;
        const int k  = (v >> 19) & 31;
        const int ol = v >> 24;

        const float4* f4 = (const float4*)(features + (size_t)in * CIN);
        const float4 f0 = f4[0], f1 = f4[1], f2 = f4[2], f3 = f4[3];
        const float4* w4 = (const float4*)(weight + k * CIN * COUT);

        float4 a0 = make_float4(0.f, 0.f, 0.f, 0.f);
        float4 a1 = a0, a2 = a0, a3 = a0;
#define CSTEP(fc, c)                         \
        {                                    \
            fma4(a0, (fc), w4[(c) * 4 + 0]); \
            fma4(a1, (fc), w4[(c) * 4 + 1]); \
            fma4(a2, (fc), w4[(c) * 4 + 2]); \
            fma4(a3, (fc), w4[(c) * 4 + 3]); \
        }
        CSTEP(f0.x,  0) CSTEP(f0.y,  1) CSTEP(f0.z,  2) CSTEP(f0.w,  3)
        CSTEP(f1.x,  4) CSTEP(f1.y,  5) CSTEP(f1.z,  6) CSTEP(f1.w,  7)
        CSTEP(f2.x,  8) CSTEP(f2.y,  9) CSTEP(f2.z, 10) CSTEP(f2.w, 11)
        CSTEP(f3.x, 12) CSTEP(f3.y, 13) CSTEP(f3.z, 14) CSTEP(f3.w, 15)
#undef CSTEP

        float* ar = acc + ol * ASTRIDE;
        atomicAdd(ar +  0, a0.x); atomicAdd(ar +  1, a0.y);
        atomicAdd(ar +  2, a0.z); atomicAdd(ar +  3, a0.w);
        atomicAdd(ar +  4, a1.x); atomicAdd(ar +  5, a1.y);
        atomicAdd(ar +  6, a1.z); atomicAdd(ar +  7, a1.w);
        atomicAdd(ar +  8, a2.x); atomicAdd(ar +  9, a2.y);
        atomicAdd(ar + 10, a2.z); atomicAdd(ar + 11, a2.w);
        atomicAdd(ar + 12, a3.x); atomicAdd(ar + 13, a3.y);
        atomicAdd(ar + 14, a3.z); atomicAdd(ar + 15, a3.w);
    }
    __syncthreads();

    const int row = b * 256 + tid;
    if (row >= NSITES) return;
    const float* a = acc + tid * ASTRIDE;
    float4 o0, o1, o2, o3;
    o0.x = a[ 0] + bias[ 0]; o0.y = a[ 1] + bias[ 1];
    o0.z = a[ 2] + bias[ 2]; o0.w = a[ 3] + bias[ 3];
    o1.x = a[ 4] + bias[ 4]; o1.y = a[ 5] + bias[ 5];
    o1.z = a[ 6] + bias[ 6]; o1.w = a[ 7] + bias[ 7];
    o2.x = a[ 8] + bias[ 8]; o2.y = a[ 9] + bias[ 9];
    o2.z = a[10] + bias[10]; o2.w = a[11] + bias[11];
    o3.x = a[12] + bias[12]; o3.y = a[13] + bias[13];
    o3.z = a[14] + bias[14]; o3.w = a[15] + bias[15];
    float4* op = (float4*)(out + (size_t)row * COUT);
    op[0] = o0; op[1] = o1; op[2] = o2; op[3] = o3;
}

// ---------------------------------------------------------------------------
extern "C" void kernel_launch(void* const* d_in, const int* in_sizes, int n_in,
                              void* d_out, int out_size, void* d_ws, size_t ws_size,
                              hipStream_t stream)
{
    const float* features  = (const float*)d_in[0];
    const float* weight    = (const float*)d_in[1];
    const float* bias      = (const float*)d_in[2];
    const int*   rules_in  = (const int*)d_in[3];
    const int*   rules_out = (const int*)d_in[4];
    float*       out       = (float*)d_out;

    int* ws       = (int*)d_ws;
    int* cur      = ws;                 // NSEG
    int* segstart = ws + 65536;         // NSEG+1
    int* entries  = ws + 131072;        // KR

    hipMemsetAsync(cur, 0, NSEG * sizeof(int), stream);

    dim3 gridKR((RPAIR + 255) / 256, KOFF);
    subhist_kernel<<<gridKR, 256, 0, stream>>>(rules_out, cur);
    seg_scan_kernel<<<1, 1024, 0, stream>>>(cur, segstart);
    scatter_kernel<<<gridKR, 256, 0, stream>>>(rules_in, rules_out, cur, entries);
    bucket_gemm_kernel<<<NBUCK, 256, 0, stream>>>(
        features, weight, bias, segstart, entries, out);
}

// Round 5
// 1382.714 us; speedup vs baseline: 1.0391x; 1.0391x over previous
//
#include <hip/hip_runtime.h>

#define NSITES 500000
#define KOFF   27
#define RPAIR  250000
#define KR     (KOFF * RPAIR)            // 6,750,000 pairs
#define CIN    16
#define COUT   16
#define NBUCK  ((NSITES + 255) / 256)    // 1954 output buckets (256 rows each)
#define ASTRIDE 17                       // LDS acc row stride (bank spread)

// ---------------- workspace layout (int32 slots) ----------------
// cur      [0,     32768)   padded counters/cursors: slot b*16 (64B/line)
// segstart [32768, 32768+NBUCK+1)
// entries  [36864, 36864+KR)            packed (in | k<<19 | o_local<<24)
// fbf16    [36864+KR, +4,000,000)       bf16 feature table [N][16] (16 MB)
#define WS_SEG  32768
#define WS_ENT  36864

// ---------------------------------------------------------------------------
// Pass 0: features f32 -> packed bf16 rows (32 B/row), RNE
// ---------------------------------------------------------------------------
__global__ __launch_bounds__(256) void convert_bf16_kernel(
    const float* __restrict__ f, uint4* __restrict__ fb)
{
    const int r = blockIdx.x * 256 + threadIdx.x;
    if (r >= NSITES) return;
    const uint4* src = (const uint4*)(f + (size_t)r * CIN);
    const uint4 a = src[0], b = src[1], c = src[2], d = src[3];
#define BF(x) (((x) + 0x7FFFu + (((x) >> 16) & 1u)) >> 16)
    uint4 o0, o1;
    o0.x = BF(a.x) | (BF(a.y) << 16);
    o0.y = BF(a.z) | (BF(a.w) << 16);
    o0.z = BF(b.x) | (BF(b.y) << 16);
    o0.w = BF(b.z) | (BF(b.w) << 16);
    o1.x = BF(c.x) | (BF(c.y) << 16);
    o1.y = BF(c.z) | (BF(c.w) << 16);
    o1.z = BF(d.x) | (BF(d.y) << 16);
    o1.w = BF(d.z) | (BF(d.w) << 16);
#undef BF
    fb[(size_t)r * 2]     = o0;
    fb[(size_t)r * 2 + 1] = o1;
}

// ---------------------------------------------------------------------------
// Pass 1: per-bucket histogram (padded counters: one per 64B line)
// ---------------------------------------------------------------------------
__global__ __launch_bounds__(256) void subhist_kernel(
    const int* __restrict__ rules_out, int* __restrict__ cur)
{
    const int k = blockIdx.y;
    const int r = blockIdx.x * blockDim.x + threadIdx.x;
    if (r >= RPAIR) return;
    const int o = rules_out[k * RPAIR + r];
    atomicAdd(cur + ((o >> 8) << 4), 1);
}

// ---------------------------------------------------------------------------
// Pass 2: exclusive scan over 1954 bucket counts -> segstart, cur=cursor
// ---------------------------------------------------------------------------
__global__ __launch_bounds__(1024) void seg_scan_kernel(
    int* __restrict__ cur, int* __restrict__ segstart)
{
    __shared__ int s[1024];
    __shared__ int base_s;
    const int t = threadIdx.x;
    if (t == 0) base_s = 0;
    __syncthreads();
    for (int chunk = 0; chunk < (NBUCK + 1023) / 1024; ++chunk) {
        const int i = chunk * 1024 + t;
        const int v = (i < NBUCK) ? cur[i << 4] : 0;
        s[t] = v;
        __syncthreads();
        for (int off = 1; off < 1024; off <<= 1) {
            int u = (t >= off) ? s[t - off] : 0;
            __syncthreads();
            s[t] += u;
            __syncthreads();
        }
        const int excl = base_s + s[t] - v;
        if (i < NBUCK) { segstart[i] = excl; cur[i << 4] = excl; }
        __syncthreads();
        if (t == 1023) base_s += s[1023];
        __syncthreads();
    }
    if (t == 0) segstart[NBUCK] = KR;
}

// ---------------------------------------------------------------------------
// Pass 3: scatter pairs into bucket-major entries (1954 frontiers, 125 KB —
// fully L2-resident, no write amplification)
// ---------------------------------------------------------------------------
__global__ __launch_bounds__(256) void scatter_kernel(
    const int* __restrict__ rules_in, const int* __restrict__ rules_out,
    int* __restrict__ cur, int* __restrict__ entries)
{
    const int k = blockIdx.y;
    const int r = blockIdx.x * blockDim.x + threadIdx.x;
    if (r >= RPAIR) return;
    const int p  = k * RPAIR + r;
    const int o  = rules_out[p];
    const int in = rules_in[p];
    const int pos = atomicAdd(cur + ((o >> 8) << 4), 1);
    entries[pos] = in | (k << 19) | ((o & 255) << 24);
}

// ---------------------------------------------------------------------------
// Pass 4: one block per bucket. LDS f32 accumulators. Per-lane random k
// weight loads hit L1 (27 KB table). 2-entry software pipeline.
// ---------------------------------------------------------------------------
__device__ __forceinline__ void fma4(float4& a, float s, const float4 w) {
    a.x = fmaf(s, w.x, a.x);
    a.y = fmaf(s, w.y, a.y);
    a.z = fmaf(s, w.z, a.z);
    a.w = fmaf(s, w.w, a.w);
}

__device__ __forceinline__ void accum_entry(
    unsigned v, const float* __restrict__ weight, float* acc, const float* f)
{
    const int k  = (v >> 19) & 31;
    const int ol = (int)(v >> 24);
    const float4* w4 = (const float4*)(weight + k * (CIN * COUT));
    float4 a0 = make_float4(0.f, 0.f, 0.f, 0.f);
    float4 a1 = a0, a2 = a0, a3 = a0;
#define CSTEP(c)                              \
    {                                         \
        const float s_ = f[c];                \
        fma4(a0, s_, w4[(c) * 4 + 0]);        \
        fma4(a1, s_, w4[(c) * 4 + 1]);        \
        fma4(a2, s_, w4[(c) * 4 + 2]);        \
        fma4(a3, s_, w4[(c) * 4 + 3]);        \
    }
    CSTEP(0)  CSTEP(1)  CSTEP(2)  CSTEP(3)
    CSTEP(4)  CSTEP(5)  CSTEP(6)  CSTEP(7)
    CSTEP(8)  CSTEP(9)  CSTEP(10) CSTEP(11)
    CSTEP(12) CSTEP(13) CSTEP(14) CSTEP(15)
#undef CSTEP
    float* ar = acc + ol * ASTRIDE;
    atomicAdd(ar +  0, a0.x); atomicAdd(ar +  1, a0.y);
    atomicAdd(ar +  2, a0.z); atomicAdd(ar +  3, a0.w);
    atomicAdd(ar +  4, a1.x); atomicAdd(ar +  5, a1.y);
    atomicAdd(ar +  6, a1.z); atomicAdd(ar +  7, a1.w);
    atomicAdd(ar +  8, a2.x); atomicAdd(ar +  9, a2.y);
    atomicAdd(ar + 10, a2.z); atomicAdd(ar + 11, a2.w);
    atomicAdd(ar + 12, a3.x); atomicAdd(ar + 13, a3.y);
    atomicAdd(ar + 14, a3.z); atomicAdd(ar + 15, a3.w);
}

__device__ __forceinline__ void unpack_bf16(const uint4 pa, const uint4 pb,
                                            float* f)
{
    f[0]  = __uint_as_float(pa.x << 16); f[1]  = __uint_as_float(pa.x & 0xFFFF0000u);
    f[2]  = __uint_as_float(pa.y << 16); f[3]  = __uint_as_float(pa.y & 0xFFFF0000u);
    f[4]  = __uint_as_float(pa.z << 16); f[5]  = __uint_as_float(pa.z & 0xFFFF0000u);
    f[6]  = __uint_as_float(pa.w << 16); f[7]  = __uint_as_float(pa.w & 0xFFFF0000u);
    f[8]  = __uint_as_float(pb.x << 16); f[9]  = __uint_as_float(pb.x & 0xFFFF0000u);
    f[10] = __uint_as_float(pb.y << 16); f[11] = __uint_as_float(pb.y & 0xFFFF0000u);
    f[12] = __uint_as_float(pb.z << 16); f[13] = __uint_as_float(pb.z & 0xFFFF0000u);
    f[14] = __uint_as_float(pb.w << 16); f[15] = __uint_as_float(pb.w & 0xFFFF0000u);
}

template <int BF16>
__global__ __launch_bounds__(256) void bucket_gemm_kernel(
    const float* __restrict__ features,
    const uint4* __restrict__ fbf16,
    const float* __restrict__ weight,
    const float* __restrict__ bias,
    const int*   __restrict__ segstart,
    const int*   __restrict__ entries,
    float*       __restrict__ out)
{
    __shared__ float acc[256 * ASTRIDE];
    const int b   = blockIdx.x;
    const int tid = threadIdx.x;

    for (int i = tid; i < 256 * ASTRIDE; i += 256) acc[i] = 0.f;
    __syncthreads();

    const int s = segstart[b];
    const int e = segstart[b + 1];

    for (int i = s + tid; i < e; i += 512) {
        const int j = i + 256;
        const unsigned v0 = (unsigned)entries[i];
        const unsigned v1 = (j < e) ? (unsigned)entries[j] : 0u;
        const int in0 = v0 & 0x7FFFF;
        const int in1 = v1 & 0x7FFFF;

        // issue both rows' loads before either FMA block (2 rows in flight)
        float f0[16], f1[16];
        uint4 p0a, p0b, p1a, p1b;
        float4 q00, q01, q02, q03, q10, q11, q12, q13;
        if (BF16) {
            p0a = fbf16[(size_t)in0 * 2];
            p0b = fbf16[(size_t)in0 * 2 + 1];
        } else {
            const float4* f4 = (const float4*)(features + (size_t)in0 * CIN);
            q00 = f4[0]; q01 = f4[1]; q02 = f4[2]; q03 = f4[3];
        }
        if (j < e) {
            if (BF16) {
                p1a = fbf16[(size_t)in1 * 2];
                p1b = fbf16[(size_t)in1 * 2 + 1];
            } else {
                const float4* f4 = (const float4*)(features + (size_t)in1 * CIN);
                q10 = f4[0]; q11 = f4[1]; q12 = f4[2]; q13 = f4[3];
            }
        }

        if (BF16) {
            unpack_bf16(p0a, p0b, f0);
        } else {
            f0[0]=q00.x; f0[1]=q00.y; f0[2]=q00.z; f0[3]=q00.w;
            f0[4]=q01.x; f0[5]=q01.y; f0[6]=q01.z; f0[7]=q01.w;
            f0[8]=q02.x; f0[9]=q02.y; f0[10]=q02.z; f0[11]=q02.w;
            f0[12]=q03.x; f0[13]=q03.y; f0[14]=q03.z; f0[15]=q03.w;
        }
        accum_entry(v0, weight, acc, f0);

        if (j < e) {
            if (BF16) {
                unpack_bf16(p1a, p1b, f1);
            } else {
                f1[0]=q10.x; f1[1]=q10.y; f1[2]=q10.z; f1[3]=q10.w;
                f1[4]=q11.x; f1[5]=q11.y; f1[6]=q11.z; f1[7]=q11.w;
                f1[8]=q12.x; f1[9]=q12.y; f1[10]=q12.z; f1[11]=q12.w;
                f1[12]=q13.x; f1[13]=q13.y; f1[14]=q13.z; f1[15]=q13.w;
            }
            accum_entry(v1, weight, acc, f1);
        }
    }
    __syncthreads();

    const int row = b * 256 + tid;
    if (row >= NSITES) return;
    const float* a = acc + tid * ASTRIDE;
    float4 o0, o1, o2, o3;
    o0.x = a[ 0] + bias[ 0]; o0.y = a[ 1] + bias[ 1];
    o0.z = a[ 2] + bias[ 2]; o0.w = a[ 3] + bias[ 3];
    o1.x = a[ 4] + bias[ 4]; o1.y = a[ 5] + bias[ 5];
    o1.z = a[ 6] + bias[ 6]; o1.w = a[ 7] + bias[ 7];
    o2.x = a[ 8] + bias[ 8]; o2.y = a[ 9] + bias[ 9];
    o2.z = a[10] + bias[10]; o2.w = a[11] + bias[11];
    o3.x = a[12] + bias[12]; o3.y = a[13] + bias[13];
    o3.z = a[14] + bias[14]; o3.w = a[15] + bias[15];
    float4* op = (float4*)(out + (size_t)row * COUT);
    op[0] = o0; op[1] = o1; op[2] = o2; op[3] = o3;
}

// ---------------------------------------------------------------------------
extern "C" void kernel_launch(void* const* d_in, const int* in_sizes, int n_in,
                              void* d_out, int out_size, void* d_ws, size_t ws_size,
                              hipStream_t stream)
{
    const float* features  = (const float*)d_in[0];
    const float* weight    = (const float*)d_in[1];
    const float* bias      = (const float*)d_in[2];
    const int*   rules_in  = (const int*)d_in[3];
    const int*   rules_out = (const int*)d_in[4];
    float*       out       = (float*)d_out;

    int*   ws       = (int*)d_ws;
    int*   cur      = ws;
    int*   segstart = ws + WS_SEG;
    int*   entries  = ws + WS_ENT;
    uint4* fbf16    = (uint4*)(ws + WS_ENT + KR);

    const size_t need_bf16 = (size_t)(WS_ENT + KR + 4000000) * 4;
    const bool use_bf16 = (ws_size >= need_bf16);

    hipMemsetAsync(cur, 0, 32768 * sizeof(int), stream);

    if (use_bf16) {
        convert_bf16_kernel<<<(NSITES + 255) / 256, 256, 0, stream>>>(
            features, fbf16);
    }

    dim3 gridKR((RPAIR + 255) / 256, KOFF);
    subhist_kernel<<<gridKR, 256, 0, stream>>>(rules_out, cur);
    seg_scan_kernel<<<1, 1024, 0, stream>>>(cur, segstart);
    scatter_kernel<<<gridKR, 256, 0, stream>>>(rules_in, rules_out, cur, entries);

    if (use_bf16) {
        bucket_gemm_kernel<1><<<NBUCK, 256, 0, stream>>>(
            features, fbf16, weight, bias, segstart, entries, out);
    } else {
        bucket_gemm_kernel<0><<<NBUCK, 256, 0, stream>>>(
            features, fbf16, weight, bias, segstart, entries, out);
    }
}

// Round 6
// 1245.606 us; speedup vs baseline: 1.1535x; 1.1101x over previous
//
#include <hip/hip_runtime.h>

#define NSITES 500000
#define KOFF   27
#define RPAIR  250000
#define KR     (KOFF * RPAIR)            // 6,750,000 pairs
#define CIN    16
#define COUT   16
#define NBUCK  ((NSITES + 255) / 256)    // 1954 output buckets (256 rows each)
#define NXCD   8
#define NSEG2  (NBUCK * NXCD)            // 15632 (bucket-major, xcd-minor)
#define ASTRIDE 17                       // LDS acc row stride (bank spread)

// cursor slot for (bucket b, xcd x): x-major, 4-int (16B) padding.
// A 64B line holds 4 buckets of the SAME xcd -> no cross-XCD line bouncing.
#define CURIDX(b, x) ((x) * (NBUCK * 4) + (b) * 4)

// ---------------- workspace layout (int32 slots) ----------------
// cur      [0,      65536)    padded per-(b,x) counters/cursors
// segstart [65536,  65536+NSEG2+1)
// entries  [81920,  81920+KR)           packed (in | k<<19 | o_local<<24)
// fbf16    [81920+KR, +4,000,000)       bf16 feature table [N][16] (16 MB)
#define WS_SEG  65536
#define WS_ENT  81920

// ---------------------------------------------------------------------------
// Pass 0: features f32 -> packed bf16 rows (32 B/row), RNE
// ---------------------------------------------------------------------------
__global__ __launch_bounds__(256) void convert_bf16_kernel(
    const float* __restrict__ f, uint4* __restrict__ fb)
{
    const int r = blockIdx.x * 256 + threadIdx.x;
    if (r >= NSITES) return;
    const uint4* src = (const uint4*)(f + (size_t)r * CIN);
    const uint4 a = src[0], b = src[1], c = src[2], d = src[3];
#define BF(x) (((x) + 0x7FFFu + (((x) >> 16) & 1u)) >> 16)
    uint4 o0, o1;
    o0.x = BF(a.x) | (BF(a.y) << 16);
    o0.y = BF(a.z) | (BF(a.w) << 16);
    o0.z = BF(b.x) | (BF(b.y) << 16);
    o0.w = BF(b.z) | (BF(b.w) << 16);
    o1.x = BF(c.x) | (BF(c.y) << 16);
    o1.y = BF(c.z) | (BF(c.w) << 16);
    o1.z = BF(d.x) | (BF(d.y) << 16);
    o1.w = BF(d.z) | (BF(d.w) << 16);
#undef BF
    fb[(size_t)r * 2]     = o0;
    fb[(size_t)r * 2 + 1] = o1;
}

// ---------------------------------------------------------------------------
// Pass 1: per-(bucket, xcd) histogram. x derived from linear block id, which
// is identical in hist & scatter (same grid) -> counts always consistent.
// ---------------------------------------------------------------------------
__global__ __launch_bounds__(256) void subhist_kernel(
    const int* __restrict__ rules_out, int* __restrict__ cur)
{
    const int k = blockIdx.y;
    const int r = blockIdx.x * blockDim.x + threadIdx.x;
    if (r >= RPAIR) return;
    const int x = (blockIdx.y * gridDim.x + blockIdx.x) & (NXCD - 1);
    const int o = rules_out[k * RPAIR + r];
    atomicAdd(cur + CURIDX(o >> 8, x), 1);
}

// ---------------------------------------------------------------------------
// Pass 2: exclusive scan over 15632 (b-major, x-minor) counts
// ---------------------------------------------------------------------------
__global__ __launch_bounds__(1024) void seg_scan_kernel(
    int* __restrict__ cur, int* __restrict__ segstart)
{
    __shared__ int s[1024];
    __shared__ int base_s;
    const int t = threadIdx.x;
    if (t == 0) base_s = 0;
    __syncthreads();
    for (int chunk = 0; chunk < (NSEG2 + 1023) / 1024; ++chunk) {
        const int i = chunk * 1024 + t;          // seg id = b*8 + x
        const int b = i >> 3, x = i & 7;
        const int v = (i < NSEG2) ? cur[CURIDX(b, x)] : 0;
        s[t] = v;
        __syncthreads();
        for (int off = 1; off < 1024; off <<= 1) {
            int u = (t >= off) ? s[t - off] : 0;
            __syncthreads();
            s[t] += u;
            __syncthreads();
        }
        const int excl = base_s + s[t] - v;
        if (i < NSEG2) { segstart[i] = excl; cur[CURIDX(b, x)] = excl; }
        __syncthreads();
        if (t == 1023) base_s += s[1023];
        __syncthreads();
    }
    if (t == 0) segstart[NSEG2] = KR;
}

// ---------------------------------------------------------------------------
// Pass 3: scatter into per-(bucket,xcd) sub-lists. Each frontier line is
// written by one XCD only -> fills while L2-resident, no write amplification.
// ---------------------------------------------------------------------------
__global__ __launch_bounds__(256) void scatter_kernel(
    const int* __restrict__ rules_in, const int* __restrict__ rules_out,
    int* __restrict__ cur, int* __restrict__ entries)
{
    const int k = blockIdx.y;
    const int r = blockIdx.x * blockDim.x + threadIdx.x;
    if (r >= RPAIR) return;
    const int x = (blockIdx.y * gridDim.x + blockIdx.x) & (NXCD - 1);
    const int p  = k * RPAIR + r;
    const int o  = rules_out[p];
    const int in = rules_in[p];
    const int pos = atomicAdd(cur + CURIDX(o >> 8, x), 1);
    entries[pos] = in | (k << 19) | ((o & 255) << 24);
}

// ---------------------------------------------------------------------------
// Pass 4: one block per bucket; bucket's entries are contiguous:
// [segstart[8b], segstart[8b+8]). LDS f32 accumulators; 4-deep pipeline.
// ---------------------------------------------------------------------------
__device__ __forceinline__ void fma4(float4& a, float s, const float4 w) {
    a.x = fmaf(s, w.x, a.x);
    a.y = fmaf(s, w.y, a.y);
    a.z = fmaf(s, w.z, a.z);
    a.w = fmaf(s, w.w, a.w);
}

__device__ __forceinline__ void accum_packed(
    unsigned v, const uint4 pa, const uint4 pb,
    const float* __restrict__ weight, float* acc)
{
    float f[16];
    f[0]  = __uint_as_float(pa.x << 16); f[1]  = __uint_as_float(pa.x & 0xFFFF0000u);
    f[2]  = __uint_as_float(pa.y << 16); f[3]  = __uint_as_float(pa.y & 0xFFFF0000u);
    f[4]  = __uint_as_float(pa.z << 16); f[5]  = __uint_as_float(pa.z & 0xFFFF0000u);
    f[6]  = __uint_as_float(pa.w << 16); f[7]  = __uint_as_float(pa.w & 0xFFFF0000u);
    f[8]  = __uint_as_float(pb.x << 16); f[9]  = __uint_as_float(pb.x & 0xFFFF0000u);
    f[10] = __uint_as_float(pb.y << 16); f[11] = __uint_as_float(pb.y & 0xFFFF0000u);
    f[12] = __uint_as_float(pb.z << 16); f[13] = __uint_as_float(pb.z & 0xFFFF0000u);
    f[14] = __uint_as_float(pb.w << 16); f[15] = __uint_as_float(pb.w & 0xFFFF0000u);

    const int k  = (v >> 19) & 31;
    const int ol = (int)(v >> 24);
    const float4* w4 = (const float4*)(weight + k * (CIN * COUT));
    float4 a0 = make_float4(0.f, 0.f, 0.f, 0.f);
    float4 a1 = a0, a2 = a0, a3 = a0;
#define CSTEP(c)                              \
    {                                         \
        const float s_ = f[c];                \
        fma4(a0, s_, w4[(c) * 4 + 0]);        \
        fma4(a1, s_, w4[(c) * 4 + 1]);        \
        fma4(a2, s_, w4[(c) * 4 + 2]);        \
        fma4(a3, s_, w4[(c) * 4 + 3]);        \
    }
    CSTEP(0)  CSTEP(1)  CSTEP(2)  CSTEP(3)
    CSTEP(4)  CSTEP(5)  CSTEP(6)  CSTEP(7)
    CSTEP(8)  CSTEP(9)  CSTEP(10) CSTEP(11)
    CSTEP(12) CSTEP(13) CSTEP(14) CSTEP(15)
#undef CSTEP
    float* ar = acc + ol * ASTRIDE;
    atomicAdd(ar +  0, a0.x); atomicAdd(ar +  1, a0.y);
    atomicAdd(ar +  2, a0.z); atomicAdd(ar +  3, a0.w);
    atomicAdd(ar +  4, a1.x); atomicAdd(ar +  5, a1.y);
    atomicAdd(ar +  6, a1.z); atomicAdd(ar +  7, a1.w);
    atomicAdd(ar +  8, a2.x); atomicAdd(ar +  9, a2.y);
    atomicAdd(ar + 10, a2.z); atomicAdd(ar + 11, a2.w);
    atomicAdd(ar + 12, a3.x); atomicAdd(ar + 13, a3.y);
    atomicAdd(ar + 14, a3.z); atomicAdd(ar + 15, a3.w);
}

__global__ __launch_bounds__(256) void bucket_gemm_bf16_kernel(
    const uint4* __restrict__ fbf16,
    const float* __restrict__ weight,
    const float* __restrict__ bias,
    const int*   __restrict__ segstart,
    const int*   __restrict__ entries,
    float*       __restrict__ out)
{
    __shared__ float acc[256 * ASTRIDE];
    const int b   = blockIdx.x;
    const int tid = threadIdx.x;

    for (int i = tid; i < 256 * ASTRIDE; i += 256) acc[i] = 0.f;
    __syncthreads();

    const int s = segstart[b * NXCD];
    const int e = segstart[b * NXCD + NXCD];

    for (int i0 = s + tid; i0 < e; i0 += 1024) {
        const int i1 = i0 + 256, i2 = i0 + 512, i3 = i0 + 768;
        const unsigned v0 = (unsigned)entries[i0];
        const unsigned v1 = (i1 < e) ? (unsigned)entries[i1] : 0u;
        const unsigned v2 = (i2 < e) ? (unsigned)entries[i2] : 0u;
        const unsigned v3 = (i3 < e) ? (unsigned)entries[i3] : 0u;

        // issue all feature loads before any FMA block (4 rows in flight)
        uint4 p0a, p0b, p1a, p1b, p2a, p2b, p3a, p3b;
        {
            const size_t r0 = (size_t)(v0 & 0x7FFFF) * 2;
            p0a = fbf16[r0]; p0b = fbf16[r0 + 1];
        }
        if (i1 < e) { const size_t r1 = (size_t)(v1 & 0x7FFFF) * 2;
                      p1a = fbf16[r1]; p1b = fbf16[r1 + 1]; }
        if (i2 < e) { const size_t r2 = (size_t)(v2 & 0x7FFFF) * 2;
                      p2a = fbf16[r2]; p2b = fbf16[r2 + 1]; }
        if (i3 < e) { const size_t r3 = (size_t)(v3 & 0x7FFFF) * 2;
                      p3a = fbf16[r3]; p3b = fbf16[r3 + 1]; }

        accum_packed(v0, p0a, p0b, weight, acc);
        if (i1 < e) accum_packed(v1, p1a, p1b, weight, acc);
        if (i2 < e) accum_packed(v2, p2a, p2b, weight, acc);
        if (i3 < e) accum_packed(v3, p3a, p3b, weight, acc);
    }
    __syncthreads();

    const int row = b * 256 + tid;
    if (row >= NSITES) return;
    const float* a = acc + tid * ASTRIDE;
    float4 o0, o1, o2, o3;
    o0.x = a[ 0] + bias[ 0]; o0.y = a[ 1] + bias[ 1];
    o0.z = a[ 2] + bias[ 2]; o0.w = a[ 3] + bias[ 3];
    o1.x = a[ 4] + bias[ 4]; o1.y = a[ 5] + bias[ 5];
    o1.z = a[ 6] + bias[ 6]; o1.w = a[ 7] + bias[ 7];
    o2.x = a[ 8] + bias[ 8]; o2.y = a[ 9] + bias[ 9];
    o2.z = a[10] + bias[10]; o2.w = a[11] + bias[11];
    o3.x = a[12] + bias[12]; o3.y = a[13] + bias[13];
    o3.z = a[14] + bias[14]; o3.w = a[15] + bias[15];
    float4* op = (float4*)(out + (size_t)row * COUT);
    op[0] = o0; op[1] = o1; op[2] = o2; op[3] = o3;
}

// f32 fallback (only if ws too small for the bf16 table)
__global__ __launch_bounds__(256) void bucket_gemm_f32_kernel(
    const float* __restrict__ features,
    const float* __restrict__ weight,
    const float* __restrict__ bias,
    const int*   __restrict__ segstart,
    const int*   __restrict__ entries,
    float*       __restrict__ out)
{
    __shared__ float acc[256 * ASTRIDE];
    const int b   = blockIdx.x;
    const int tid = threadIdx.x;
    for (int i = tid; i < 256 * ASTRIDE; i += 256) acc[i] = 0.f;
    __syncthreads();

    const int s = segstart[b * NXCD];
    const int e = segstart[b * NXCD + NXCD];

    for (int i = s + tid; i < e; i += 256) {
        const unsigned v = (unsigned)entries[i];
        const int in = v & 0x7FFFF;
        const int k  = (v >> 19) & 31;
        const int ol = (int)(v >> 24);
        const float4* f4 = (const float4*)(features + (size_t)in * CIN);
        const float4 f0 = f4[0], f1 = f4[1], f2 = f4[2], f3 = f4[3];
        const float4* w4 = (const float4*)(weight + k * (CIN * COUT));
        float4 a0 = make_float4(0.f, 0.f, 0.f, 0.f);
        float4 a1 = a0, a2 = a0, a3 = a0;
#define CSTEP(fc, c)                         \
        {                                    \
            fma4(a0, (fc), w4[(c) * 4 + 0]); \
            fma4(a1, (fc), w4[(c) * 4 + 1]); \
            fma4(a2, (fc), w4[(c) * 4 + 2]); \
            fma4(a3, (fc), w4[(c) * 4 + 3]); \
        }
        CSTEP(f0.x,  0) CSTEP(f0.y,  1) CSTEP(f0.z,  2) CSTEP(f0.w,  3)
        CSTEP(f1.x,  4) CSTEP(f1.y,  5) CSTEP(f1.z,  6) CSTEP(f1.w,  7)
        CSTEP(f2.x,  8) CSTEP(f2.y,  9) CSTEP(f2.z, 10) CSTEP(f2.w, 11)
        CSTEP(f3.x, 12) CSTEP(f3.y, 13) CSTEP(f3.z, 14) CSTEP(f3.w, 15)
#undef CSTEP
        float* ar = acc + ol * ASTRIDE;
        atomicAdd(ar +  0, a0.x); atomicAdd(ar +  1, a0.y);
        atomicAdd(ar +  2, a0.z); atomicAdd(ar +  3, a0.w);
        atomicAdd(ar +  4, a1.x); atomicAdd(ar +  5, a1.y);
        atomicAdd(ar +  6, a1.z); atomicAdd(ar +  7, a1.w);
        atomicAdd(ar +  8, a2.x); atomicAdd(ar +  9, a2.y);
        atomicAdd(ar + 10, a2.z); atomicAdd(ar + 11, a2.w);
        atomicAdd(ar + 12, a3.x); atomicAdd(ar + 13, a3.y);
        atomicAdd(ar + 14, a3.z); atomicAdd(ar + 15, a3.w);
    }
    __syncthreads();

    const int row = b * 256 + tid;
    if (row >= NSITES) return;
    const float* a = acc + tid * ASTRIDE;
    float4 o0, o1, o2, o3;
    o0.x = a[ 0] + bias[ 0]; o0.y = a[ 1] + bias[ 1];
    o0.z = a[ 2] + bias[ 2]; o0.w = a[ 3] + bias[ 3];
    o1.x = a[ 4] + bias[ 4]; o1.y = a[ 5] + bias[ 5];
    o1.z = a[ 6] + bias[ 6]; o1.w = a[ 7] + bias[ 7];
    o2.x = a[ 8] + bias[ 8]; o2.y = a[ 9] + bias[ 9];
    o2.z = a[10] + bias[10]; o2.w = a[11] + bias[11];
    o3.x = a[12] + bias[12]; o3.y = a[13] + bias[13];
    o3.z = a[14] + bias[14]; o3.w = a[15] + bias[15];
    float4* op = (float4*)(out + (size_t)row * COUT);
    op[0] = o0; op[1] = o1; op[2] = o2; op[3] = o3;
}

// ---------------------------------------------------------------------------
extern "C" void kernel_launch(void* const* d_in, const int* in_sizes, int n_in,
                              void* d_out, int out_size, void* d_ws, size_t ws_size,
                              hipStream_t stream)
{
    const float* features  = (const float*)d_in[0];
    const float* weight    = (const float*)d_in[1];
    const float* bias      = (const float*)d_in[2];
    const int*   rules_in  = (const int*)d_in[3];
    const int*   rules_out = (const int*)d_in[4];
    float*       out       = (float*)d_out;

    int*   ws       = (int*)d_ws;
    int*   cur      = ws;
    int*   segstart = ws + WS_SEG;
    int*   entries  = ws + WS_ENT;
    uint4* fbf16    = (uint4*)(ws + WS_ENT + KR);

    const size_t need_bf16 = (size_t)(WS_ENT + KR + 4000000) * 4;
    const bool use_bf16 = (ws_size >= need_bf16);

    hipMemsetAsync(cur, 0, NXCD * NBUCK * 4 * sizeof(int), stream);

    if (use_bf16) {
        convert_bf16_kernel<<<(NSITES + 255) / 256, 256, 0, stream>>>(
            features, fbf16);
    }

    dim3 gridKR((RPAIR + 255) / 256, KOFF);
    subhist_kernel<<<gridKR, 256, 0, stream>>>(rules_out, cur);
    seg_scan_kernel<<<1, 1024, 0, stream>>>(cur, segstart);
    scatter_kernel<<<gridKR, 256, 0, stream>>>(rules_in, rules_out, cur, entries);

    if (use_bf16) {
        bucket_gemm_bf16_kernel<<<NBUCK, 256, 0, stream>>>(
            fbf16, weight, bias, segstart, entries, out);
    } else {
        bucket_gemm_f32_kernel<<<NBUCK, 256, 0, stream>>>(
            features, weight, bias, segstart, entries, out);
    }
}

// Round 7
// 927.018 us; speedup vs baseline: 1.5499x; 1.3437x over previous
//
#include <hip/hip_runtime.h>

#define NSITES 500000
#define KOFF   27
#define RPAIR  250000
#define KR     (KOFF * RPAIR)            // 6,750,000 pairs
#define CIN    16
#define COUT   16
#define NBUCK  1954                      // output bucket = o >> 8
#define NBLK   256                       // preprocessing blocks
#define CHUNK  ((KR + NBLK - 1) / NBLK)  // 26368 pairs per block
#define NSLICE 31                        // input slice = in >> 14 (0..30)
#define ASTRIDE 17                       // LDS acc row stride
#define IDXCAP 4096                      // per-bucket LDS idx capacity

// ---------------- workspace layout (BYTE offsets) ----------------
// countsT ushort[NBLK][NBUCK]   [0,          1,000,448)
// PT      ushort[NBLK][NBUCK]   [1,000,448,  2,000,896)
// Ttot    int[NBUCK]            [2,000,896,  2,008,712)
// cstart  int[NBUCK+1]          [2,008,712,  2,016,532)
// entries uint[KR]              [2,016,544,  29,016,544)
// fbf16   uint4[NSITES*2]       [29,016,544, 45,016,544)
#define OFF_PT     1000448
#define OFF_TTOT   2000896
#define OFF_CSTART 2008712
#define OFF_ENT    2016544
#define OFF_FBF16  29016544
#define NEED_BF16  45016544
#define NEED_F32   29016544

// ---------------------------------------------------------------------------
// Pass 0: features f32 -> packed bf16 rows (32 B/row), RNE
// ---------------------------------------------------------------------------
__global__ __launch_bounds__(256) void convert_bf16_kernel(
    const float* __restrict__ f, uint4* __restrict__ fb)
{
    const int r = blockIdx.x * 256 + threadIdx.x;
    if (r >= NSITES) return;
    const uint4* src = (const uint4*)(f + (size_t)r * CIN);
    const uint4 a = src[0], b = src[1], c = src[2], d = src[3];
#define BF(x) (((x) + 0x7FFFu + (((x) >> 16) & 1u)) >> 16)
    uint4 o0, o1;
    o0.x = BF(a.x) | (BF(a.y) << 16);
    o0.y = BF(a.z) | (BF(a.w) << 16);
    o0.z = BF(b.x) | (BF(b.y) << 16);
    o0.w = BF(b.z) | (BF(b.w) << 16);
    o1.x = BF(c.x) | (BF(c.y) << 16);
    o1.y = BF(c.z) | (BF(c.w) << 16);
    o1.z = BF(d.x) | (BF(d.y) << 16);
    o1.w = BF(d.z) | (BF(d.w) << 16);
#undef BF
    fb[(size_t)r * 2]     = o0;
    fb[(size_t)r * 2 + 1] = o1;
}

// ---------------------------------------------------------------------------
// passA: per-(block, bucket) counts via LDS. No global atomics.
// ---------------------------------------------------------------------------
__global__ __launch_bounds__(256) void passA_kernel(
    const int* __restrict__ rules_out, unsigned short* __restrict__ countsT)
{
    __shared__ unsigned cnt[NBUCK];
    for (int i = threadIdx.x; i < NBUCK; i += 256) cnt[i] = 0;
    __syncthreads();
    const int base = blockIdx.x * CHUNK;
    const int end  = (base + CHUNK < KR) ? base + CHUNK : KR;
    for (int p = base + threadIdx.x; p < end; p += 256)
        atomicAdd(&cnt[rules_out[p] >> 8], 1u);
    __syncthreads();
    unsigned short* row = countsT + (size_t)blockIdx.x * NBUCK;
    for (int i = threadIdx.x; i < NBUCK; i += 256)
        row[i] = (unsigned short)cnt[i];
}

// ---------------------------------------------------------------------------
// scanK1: per-bucket prefix over blocks -> PT[blk][b]; totals -> Ttot[b]
// ---------------------------------------------------------------------------
__global__ __launch_bounds__(256) void scanK1_kernel(
    const unsigned short* __restrict__ countsT,
    unsigned short* __restrict__ PT, int* __restrict__ Ttot)
{
    const int c = blockIdx.x * 256 + threadIdx.x;
    if (c >= NBUCK) return;
    unsigned run = 0;
    for (int g = 0; g < NBLK; ++g) {
        PT[(size_t)g * NBUCK + c] = (unsigned short)run;
        run += countsT[(size_t)g * NBUCK + c];
    }
    Ttot[c] = (int)run;
}

// ---------------------------------------------------------------------------
// scanK2: exclusive scan of Ttot[1954] -> cstart (+ sentinel)
// ---------------------------------------------------------------------------
__global__ __launch_bounds__(1024) void scanK2_kernel(
    const int* __restrict__ Ttot, int* __restrict__ cstart)
{
    __shared__ int s[1024];
    __shared__ int base_s;
    const int t = threadIdx.x;
    if (t == 0) base_s = 0;
    __syncthreads();
    for (int chunk = 0; chunk < (NBUCK + 1023) / 1024; ++chunk) {
        const int i = chunk * 1024 + t;
        const int v = (i < NBUCK) ? Ttot[i] : 0;
        s[t] = v;
        __syncthreads();
        for (int off = 1; off < 1024; off <<= 1) {
            int u = (t >= off) ? s[t - off] : 0;
            __syncthreads();
            s[t] += u;
            __syncthreads();
        }
        if (i < NBUCK) cstart[i] = base_s + s[t] - v;
        __syncthreads();
        if (t == 1023) base_s += s[1023];
        __syncthreads();
    }
    if (t == 0) cstart[NBUCK] = KR;
}

// ---------------------------------------------------------------------------
// passB: deterministic placement. pos = cstart[b] + PT[blk][b] + LDS-rank.
// Runs of ~13.5 entries per (b,blk) -> dense line fills, no global atomics.
// ---------------------------------------------------------------------------
__global__ __launch_bounds__(256) void passB_kernel(
    const int* __restrict__ rules_in, const int* __restrict__ rules_out,
    const int* __restrict__ cstart, const unsigned short* __restrict__ PT,
    unsigned* __restrict__ entries)
{
    __shared__ unsigned cur[NBUCK];
    for (int i = threadIdx.x; i < NBUCK; i += 256) cur[i] = 0;
    __syncthreads();
    const int base = blockIdx.x * CHUNK;
    const int end  = (base + CHUNK < KR) ? base + CHUNK : KR;
    const unsigned short* pt = PT + (size_t)blockIdx.x * NBUCK;
    for (int p = base + threadIdx.x; p < end; p += 256) {
        const int o  = rules_out[p];
        const int in = rules_in[p];
        const int b  = o >> 8;
        const int k  = p / RPAIR;           // constant-div -> mul/shift
        const unsigned rank = atomicAdd(&cur[b], 1u);
        const int pos = cstart[b] + (int)pt[b] + (int)rank;
        entries[pos] = (unsigned)in | ((unsigned)k << 19) |
                       ((unsigned)(o & 255) << 24);
    }
}

// ---------------------------------------------------------------------------
// gemm: one block per bucket. LDS counting-sort of entry indices by input
// slice (in>>14, 31 slices of 1 MB bf16) -> slice-phased gathers hit L2.
// ---------------------------------------------------------------------------
__device__ __forceinline__ void fma4(float4& a, float s, const float4 w) {
    a.x = fmaf(s, w.x, a.x);
    a.y = fmaf(s, w.y, a.y);
    a.z = fmaf(s, w.z, a.z);
    a.w = fmaf(s, w.w, a.w);
}

template <int BF16>
__device__ __forceinline__ void process_entry(
    unsigned v, const uint4* __restrict__ fb, const float* __restrict__ feat,
    const float* __restrict__ weight, float* acc)
{
    const int in = v & 0x7FFFF;
    const int k  = (v >> 19) & 31;
    const int ol = (int)(v >> 24);
    float f[16];
    if (BF16) {
        const uint4 pa = fb[(size_t)in * 2];
        const uint4 pb = fb[(size_t)in * 2 + 1];
        f[0]  = __uint_as_float(pa.x << 16); f[1]  = __uint_as_float(pa.x & 0xFFFF0000u);
        f[2]  = __uint_as_float(pa.y << 16); f[3]  = __uint_as_float(pa.y & 0xFFFF0000u);
        f[4]  = __uint_as_float(pa.z << 16); f[5]  = __uint_as_float(pa.z & 0xFFFF0000u);
        f[6]  = __uint_as_float(pa.w << 16); f[7]  = __uint_as_float(pa.w & 0xFFFF0000u);
        f[8]  = __uint_as_float(pb.x << 16); f[9]  = __uint_as_float(pb.x & 0xFFFF0000u);
        f[10] = __uint_as_float(pb.y << 16); f[11] = __uint_as_float(pb.y & 0xFFFF0000u);
        f[12] = __uint_as_float(pb.z << 16); f[13] = __uint_as_float(pb.z & 0xFFFF0000u);
        f[14] = __uint_as_float(pb.w << 16); f[15] = __uint_as_float(pb.w & 0xFFFF0000u);
    } else {
        const float4* f4 = (const float4*)(feat + (size_t)in * CIN);
        const float4 q0 = f4[0], q1 = f4[1], q2 = f4[2], q3 = f4[3];
        f[0]=q0.x; f[1]=q0.y; f[2]=q0.z; f[3]=q0.w;
        f[4]=q1.x; f[5]=q1.y; f[6]=q1.z; f[7]=q1.w;
        f[8]=q2.x; f[9]=q2.y; f[10]=q2.z; f[11]=q2.w;
        f[12]=q3.x; f[13]=q3.y; f[14]=q3.z; f[15]=q3.w;
    }
    const float4* w4 = (const float4*)(weight + k * (CIN * COUT));
    float4 a0 = make_float4(0.f, 0.f, 0.f, 0.f);
    float4 a1 = a0, a2 = a0, a3 = a0;
#define CSTEP(c)                           \
    {                                      \
        const float s_ = f[c];             \
        fma4(a0, s_, w4[(c) * 4 + 0]);     \
        fma4(a1, s_, w4[(c) * 4 + 1]);     \
        fma4(a2, s_, w4[(c) * 4 + 2]);     \
        fma4(a3, s_, w4[(c) * 4 + 3]);     \
    }
    CSTEP(0)  CSTEP(1)  CSTEP(2)  CSTEP(3)
    CSTEP(4)  CSTEP(5)  CSTEP(6)  CSTEP(7)
    CSTEP(8)  CSTEP(9)  CSTEP(10) CSTEP(11)
    CSTEP(12) CSTEP(13) CSTEP(14) CSTEP(15)
#undef CSTEP
    float* ar = acc + ol * ASTRIDE;
    atomicAdd(ar +  0, a0.x); atomicAdd(ar +  1, a0.y);
    atomicAdd(ar +  2, a0.z); atomicAdd(ar +  3, a0.w);
    atomicAdd(ar +  4, a1.x); atomicAdd(ar +  5, a1.y);
    atomicAdd(ar +  6, a1.z); atomicAdd(ar +  7, a1.w);
    atomicAdd(ar +  8, a2.x); atomicAdd(ar +  9, a2.y);
    atomicAdd(ar + 10, a2.z); atomicAdd(ar + 11, a2.w);
    atomicAdd(ar + 12, a3.x); atomicAdd(ar + 13, a3.y);
    atomicAdd(ar + 14, a3.z); atomicAdd(ar + 15, a3.w);
}

template <int BF16>
__global__ __launch_bounds__(256) void bucket_gemm_kernel(
    const uint4* __restrict__ fb,
    const float* __restrict__ feat,
    const float* __restrict__ weight,
    const float* __restrict__ bias,
    const int*   __restrict__ cstart,
    const unsigned* __restrict__ entries,
    float*       __restrict__ out)
{
    __shared__ float acc[256 * ASTRIDE];
    __shared__ unsigned short idx[IDXCAP];
    __shared__ unsigned scnt[NSLICE];     // counts -> cursors
    __shared__ unsigned sdone;            // unused pad
    const int b   = blockIdx.x;
    const int tid = threadIdx.x;

    for (int i = tid; i < 256 * ASTRIDE; i += 256) acc[i] = 0.f;
    if (tid < NSLICE) scnt[tid] = 0;
    if (tid == 0) sdone = 0;
    __syncthreads();

    const int s0 = cstart[b];
    const int e0 = cstart[b + 1];
    const int n  = e0 - s0;
    const int nl = (n < IDXCAP) ? n : IDXCAP;

    // P1: count slices
    for (int i = tid; i < nl; i += 256) {
        const unsigned v = entries[s0 + i];
        atomicAdd(&scnt[(v & 0x7FFFFu) >> 14], 1u);
    }
    __syncthreads();
    // exclusive scan of 31 counts (single lane) -> scnt becomes cursors
    if (tid == 0) {
        unsigned run = 0;
        for (int s = 0; s < NSLICE; ++s) {
            const unsigned c = scnt[s];
            scnt[s] = run;
            run += c;
        }
    }
    __syncthreads();
    // P2: slice-sorted index list
    for (int i = tid; i < nl; i += 256) {
        const unsigned v = entries[s0 + i];
        const unsigned slot = atomicAdd(&scnt[(v & 0x7FFFFu) >> 14], 1u);
        idx[slot] = (unsigned short)i;
    }
    __syncthreads();
    // P3: process slice-ascending (phase-aligned across blocks)
    for (int j = tid; j < nl; j += 256) {
        const unsigned v = entries[s0 + (int)idx[j]];
        process_entry<BF16>(v, fb, feat, weight, acc);
    }
    // overflow tail (only if bucket > IDXCAP; never with this input)
    for (int i = nl + tid; i < n; i += 256) {
        process_entry<BF16>(entries[s0 + i], fb, feat, weight, acc);
    }
    __syncthreads();

    const int row = b * 256 + tid;
    if (row >= NSITES) return;
    const float* a = acc + tid * ASTRIDE;
    float4 o0, o1, o2, o3;
    o0.x = a[ 0] + bias[ 0]; o0.y = a[ 1] + bias[ 1];
    o0.z = a[ 2] + bias[ 2]; o0.w = a[ 3] + bias[ 3];
    o1.x = a[ 4] + bias[ 4]; o1.y = a[ 5] + bias[ 5];
    o1.z = a[ 6] + bias[ 6]; o1.w = a[ 7] + bias[ 7];
    o2.x = a[ 8] + bias[ 8]; o2.y = a[ 9] + bias[ 9];
    o2.z = a[10] + bias[10]; o2.w = a[11] + bias[11];
    o3.x = a[12] + bias[12]; o3.y = a[13] + bias[13];
    o3.z = a[14] + bias[14]; o3.w = a[15] + bias[15];
    float4* op = (float4*)(out + (size_t)row * COUT);
    op[0] = o0; op[1] = o1; op[2] = o2; op[3] = o3;
}

// ---------------------------------------------------------------------------
extern "C" void kernel_launch(void* const* d_in, const int* in_sizes, int n_in,
                              void* d_out, int out_size, void* d_ws, size_t ws_size,
                              hipStream_t stream)
{
    const float* features  = (const float*)d_in[0];
    const float* weight    = (const float*)d_in[1];
    const float* bias      = (const float*)d_in[2];
    const int*   rules_in  = (const int*)d_in[3];
    const int*   rules_out = (const int*)d_in[4];
    float*       out       = (float*)d_out;

    char* wsb = (char*)d_ws;
    unsigned short* countsT = (unsigned short*)wsb;
    unsigned short* PT      = (unsigned short*)(wsb + OFF_PT);
    int*            Ttot    = (int*)(wsb + OFF_TTOT);
    int*            cstart  = (int*)(wsb + OFF_CSTART);
    unsigned*       entries = (unsigned*)(wsb + OFF_ENT);
    uint4*          fbf16   = (uint4*)(wsb + OFF_FBF16);

    const bool use_bf16 = (ws_size >= (size_t)NEED_BF16);

    if (use_bf16) {
        convert_bf16_kernel<<<(NSITES + 255) / 256, 256, 0, stream>>>(
            features, fbf16);
    }

    passA_kernel<<<NBLK, 256, 0, stream>>>(rules_out, countsT);
    scanK1_kernel<<<(NBUCK + 255) / 256, 256, 0, stream>>>(countsT, PT, Ttot);
    scanK2_kernel<<<1, 1024, 0, stream>>>(Ttot, cstart);
    passB_kernel<<<NBLK, 256, 0, stream>>>(rules_in, rules_out, cstart, PT,
                                           entries);

    if (use_bf16) {
        bucket_gemm_kernel<1><<<NBUCK, 256, 0, stream>>>(
            fbf16, features, weight, bias, cstart, entries, out);
    } else {
        bucket_gemm_kernel<0><<<NBUCK, 256, 0, stream>>>(
            fbf16, features, weight, bias, cstart, entries, out);
    }
}